// Round 10
// baseline (4919.417 us; speedup 1.0000x reference)
//
#include <hip/hip_runtime.h>
#include <hip/hip_bf16.h>
#include <stdint.h>

// ACT (adaptive computation time) on MI355X.
// R15: fold the halting update INTO gemm2's epilogue (8th-writer protocol),
// deleting k_plite from the t-loop. R14 ledger: GEMMs at structure ceiling
// (~40% MfmaUtil); remaining ~350us = t-loop tail (3 launches/iter + gaps,
// tiny counts at t>=3). gemm2's epilogue already computes the 8 per-strip
// partials of dot(h,Wp); now each slot writer does a release-store + agent
// ACQ_REL fetch_add(rowcnt[pos]); the 8th writer sums slots in fixed index
// order (bit-identical to plite), performs the t+1 halting update and
// compacts into ridx[t+1]. t=0 halting folds into k_init (row dot already
// in-register). counts/rowcnt zeroed in k_prep. Loop = gemm1->gemm2 only:
// 24 launches (was 36). Race audit: each wave's uw[pos] read happens-before
// its slot store (data dep through pd reduction); 8th writer happens-after
// all 8 stores; cross-kernel reads sit on dispatch boundaries as before.
// GEMM cores unchanged from R14 (static LDS, R5 912-TF structure,
// accumulation order kt->pb->pa->mt->nt bit-identical).

#define THR 0.99f
typedef float4 f4;
typedef __attribute__((ext_vector_type(8))) short short8;
typedef __attribute__((ext_vector_type(4))) float f32x4;

__device__ __forceinline__ int detect_bf(const void* mask) {
  return (((const unsigned int*)mask)[0] == 0x3F803F80u) ? 1 : 0;
}

__device__ __forceinline__ float ld_in(const void* p, long i, int bf) {
  if (bf) {
    unsigned short u = ((const unsigned short*)p)[i];
    return __uint_as_float(((unsigned int)u) << 16);
  }
  return ((const float*)p)[i];
}
__device__ __forceinline__ f4 ld4(const float* p) { return *(const f4*)p; }

// truncation 3-way bf16 split: x ~= h + m + l, |err| <= 2^-24|x|
__device__ __forceinline__ void split3(float x, unsigned short& h,
                                       unsigned short& m, unsigned short& l) {
  unsigned u = __float_as_uint(x);
  h = (unsigned short)(u >> 16);
  float fh = __uint_as_float(u & 0xFFFF0000u);
  float r = x - fh;  // exact
  unsigned v = __float_as_uint(r);
  m = (unsigned short)(v >> 16);
  float fm = __uint_as_float(v & 0xFFFF0000u);
  l = (unsigned short)(__float_as_uint(r - fm) >> 16);
}

__device__ __forceinline__ void gld16(const void* g, void* l) {
  __builtin_amdgcn_global_load_lds(
      (const __attribute__((address_space(1))) void*)g,
      (__attribute__((address_space(3))) void*)l, 16, 0, 0);
}

#define MFMA16 __builtin_amdgcn_mfma_f32_16x16x32_bf16

// ---------- prep: small param conversion + edot + counters ---------------
__global__ __launch_bounds__(256) void k_prep(
    const void* mask, const void* emb, const void* Wp, const void* bp,
    const void* b1, const void* b2, float* embF, float* WpF, float* bpF,
    float* b1F, float* b2F, float* edot, int* counts, int* rowcnt) {
  int bf = detect_bf(mask);
  int tid = threadIdx.x;
  long gt = (long)blockIdx.x * 256 + tid;
  long gs = (long)gridDim.x * 256;
  for (long i = gt; i < 5632; i += gs) embF[i] = ld_in(emb, i, bf);
  for (long i = gt; i < 512; i += gs) {
    WpF[i] = ld_in(Wp, i, bf);
    b2F[i] = ld_in(b2, i, bf);
  }
  for (long i = gt; i < 2048; i += gs) b1F[i] = ld_in(b1, i, bf);
  for (long i = gt; i < 16384; i += gs) rowcnt[i] = 0;
  if (gt < 11) counts[gt] = 0;
  if (gt == 0) bpF[0] = ld_in(bp, 0, bf);
  // edot[t] = dot(emb_t, Wp): blocks 0..10, wave 0
  int lane = tid & 63, wv = tid >> 6;
  if (blockIdx.x < 11 && wv == 0) {
    int t = blockIdx.x;
    int d = lane * 8;
    float acc = 0.f;
#pragma unroll
    for (int j = 0; j < 8; ++j) {
      float wpv = ld_in(Wp, d + j, bf);
      float ev = ld_in(emb, (long)t * 512 + d + j, bf);
      acc = (j == 0) ? ev * wpv : fmaf(ev, wpv, acc);
    }
#pragma unroll
    for (int off = 32; off > 0; off >>= 1) acc += __shfl_xor(acc, off, 64);
    if (lane == 0) edot[t] = acc;
  }
}

// ---------- init: conversions + weight split + t=0 halting ----------------
// Row pass: 2048 blocks x 4 waves x 2 rows = 16384 rows. Each wave copies
// its rows to stateF, zeroes prevF, reduces dot(row,Wp), and lane 0 performs
// the t=0 halting update (hpv=0, rem=0, nup=0) + compaction into ridx[0].
__global__ __launch_bounds__(256) void k_init(
    const void* state, const void* W1, const void* W2, const void* mask,
    const void* Wp, const float* __restrict__ edot,
    const float* __restrict__ bpF, float* stateF, unsigned short* w1t,
    unsigned short* w2t, float* maskF, float* prevF, float* hp, float* rem,
    float* nup, float* uw, int* counts0, int* ridx0) {
  int bf = detect_bf(mask);
  int tid = threadIdx.x;
  int lane = tid & 63, wv = tid >> 6;
  int d = lane * 8;
  float wp[8];
#pragma unroll
  for (int j = 0; j < 8; ++j) wp[j] = ld_in(Wp, d + j, bf);
#pragma unroll 1
  for (int r = 0; r < 2; ++r) {
    long row = ((long)blockIdx.x * 4 + wv) * 2 + r;
    long base = row * 512 + d;
    float sv[8];
#pragma unroll
    for (int j = 0; j < 8; ++j) sv[j] = ld_in(state, base + j, bf);
    f4 y0, y1;
    y0.x = sv[0]; y0.y = sv[1]; y0.z = sv[2]; y0.w = sv[3];
    y1.x = sv[4]; y1.y = sv[5]; y1.z = sv[6]; y1.w = sv[7];
    *(f4*)&stateF[base] = y0;
    *(f4*)&stateF[base + 4] = y1;
    *(f4*)&prevF[base] = (f4){0.f, 0.f, 0.f, 0.f};
    *(f4*)&prevF[base + 4] = (f4){0.f, 0.f, 0.f, 0.f};
    float acc = sv[0] * wp[0];
#pragma unroll
    for (int j = 1; j < 8; ++j) acc = fmaf(sv[j], wp[j], acc);
#pragma unroll
    for (int off = 32; off > 0; off >>= 1) acc += __shfl_xor(acc, off, 64);
    if (lane == 0) {
      // t=0 halting update (same formulas as plite with hpv=rem=nup=0)
      float p = 1.0f / (1.0f + expf(-(acc + edot[0] + bpF[0])));
      float q = p;
      float nh = (q > THR) ? 1.0f : 0.0f;
      float st2 = (q <= THR) ? 1.0f : 0.0f;
      float hpn = p * st2;
      float remn = nh * (1.0f - hpn);
      hpn = hpn + nh * remn;
      nup[row] = st2 + nh;
      uw[row] = p * st2 + nh * remn;
      hp[row] = hpn;
      rem[row] = remn;
      int idx = atomicAdd(counts0, 1);
      ridx0[idx] = (int)row;
    }
  }
  long t = (long)blockIdx.x * blockDim.x + tid;
  long st = (long)gridDim.x * blockDim.x;
  // W1 [512][2048] -> W1T planes [2048][512] bf16 x3 (plane stride 1048576)
  for (long i = t; i < 1048576L; i += st) {
    float v = ld_in(W1, i, bf);
    long n = i & 2047, k = i >> 11;
    unsigned short h, m, l;
    split3(v, h, m, l);
    long o = n * 512 + k;
    w1t[o] = h;
    w1t[1048576L + o] = m;
    w1t[2097152L + o] = l;
  }
  // W2 [2048][512] -> W2T planes [512][2048] bf16 x3
  for (long i = t; i < 1048576L; i += st) {
    float v = ld_in(W2, i, bf);
    long k = i >> 9, n = i & 511;
    unsigned short h, m, l;
    split3(v, h, m, l);
    long o = n * 2048 + k;
    w2t[o] = h;
    w2t[1048576L + o] = m;
    w2t[2097152L + o] = l;
  }
  for (long i = t; i < 16384L; i += st) maskF[i] = ld_in(mask, i, bf);
}

// LDS (static, both GEMMs): Au fp32 [4 q][2 h][128 rows][4] = 16 KB;
// Bs bf16 [3 p][4 q][128 rows][8] = 24 KB; gemm1 adds embS[512] = 2 KB.
// Stage region = 1KB (64 lanes x 16B); R5 layouts, 0 bank conflicts verified.

// ---------- GEMM1: U = relu((state[ridx]+emb) * W1 + b1) -> U fp32 --------
__global__ __launch_bounds__(256) void k_gemm1(
    const float* __restrict__ stateF, const float* __restrict__ embT,
    const unsigned short* __restrict__ w1t, const float* __restrict__ b1F,
    const int* __restrict__ count, const int* __restrict__ ridx,
    float* __restrict__ U, int c0, int mc) {
  int Ma = *count;
  int mEnd = c0 + mc;
  if (Ma < mEnd) mEnd = Ma;
  int f = blockIdx.x;
  int x = f & 7, s = f >> 3;
  int n0 = (x * 2 + (s & 1)) * 128;
  int m0 = c0 + (s >> 1) * 128;
  if (m0 >= mEnd) return;
  __shared__ __align__(16) float Au[4][2][128][4];          // 16 KB fp32 A
  __shared__ __align__(16) unsigned short Bs[3][4][128][8]; // 24 KB B planes
  __shared__ __align__(16) float embS[512];
  int tid = threadIdx.x;
  int lane = tid & 63, wv = tid >> 6;
  int quad = lane >> 4, ln15 = lane & 15;
  int wm = (wv >> 1) << 6, wn = (wv & 1) << 6;
  if (tid < 128) *(f4*)&embS[tid * 4] = ld4(embT + tid * 4);
  int rr0 = m0 + lane;
  if (rr0 >= mEnd) rr0 = mEnd - 1;
  int rr1 = m0 + 64 + lane;
  if (rr1 >= mEnd) rr1 = mEnd - 1;
  long pos0 = ridx[rr0], pos1 = ridx[rr1];
  f32x4 acc[4][4];
#pragma unroll
  for (int i = 0; i < 4; i++)
#pragma unroll
    for (int j = 0; j < 4; j++) acc[i][j] = (f32x4)0.f;
#pragma unroll 1
  for (int kt = 0; kt < 16; ++kt) {
    __syncthreads();
#pragma unroll
    for (int i = 0; i < 4; ++i) {  // A staging fp32 gather
      int g = wv + 4 * i;
      int q = g >> 2, h = (g >> 1) & 1, rh = g & 1;
      long po = rh ? pos1 : pos0;
      gld16(stateF + po * 512 + kt * 32 + q * 8 + h * 4,
            &Au[q][h][rh * 64][0]);
    }
#pragma unroll
    for (int i = 0; i < 6; ++i) {  // B staging
      int g = wv + 4 * i;
      int p = g >> 3, q = (g >> 1) & 3, rh = g & 1;
      long n = n0 + rh * 64 + lane;
      gld16(w1t + (long)p * 1048576L + n * 512 + kt * 32 + q * 8,
            &Bs[p][q][rh * 64][0]);
    }
    __syncthreads();
    float es[8];
    {
      f4 e0 = *(const f4*)&embS[kt * 32 + quad * 8];
      f4 e1 = *(const f4*)&embS[kt * 32 + quad * 8 + 4];
      es[0] = e0.x; es[1] = e0.y; es[2] = e0.z; es[3] = e0.w;
      es[4] = e1.x; es[5] = e1.y; es[6] = e1.z; es[7] = e1.w;
    }
    short8 af[3][4];
#pragma unroll
    for (int mt = 0; mt < 4; ++mt) {
      int row = wm + mt * 16 + ln15;
      f4 x0 = *(const f4*)&Au[quad][0][row][0];
      f4 x1 = *(const f4*)&Au[quad][1][row][0];
      float xs[8];
      xs[0] = x0.x + es[0]; xs[1] = x0.y + es[1];
      xs[2] = x0.z + es[2]; xs[3] = x0.w + es[3];
      xs[4] = x1.x + es[4]; xs[5] = x1.y + es[5];
      xs[6] = x1.z + es[6]; xs[7] = x1.w + es[7];
#pragma unroll
      for (int j = 0; j < 8; ++j) {
        unsigned short h_, m_, l_;
        split3(xs[j], h_, m_, l_);
        ((unsigned short*)&af[0][mt])[j] = h_;
        ((unsigned short*)&af[1][mt])[j] = m_;
        ((unsigned short*)&af[2][mt])[j] = l_;
      }
    }
#pragma unroll
    for (int pb = 0; pb < 3; ++pb) {
      short8 bfr[4];
#pragma unroll
      for (int nt = 0; nt < 4; ++nt)
        bfr[nt] = *(const short8*)&Bs[pb][quad][wn + nt * 16 + ln15][0];
      int npa = (pb == 0) ? 3 : ((pb == 1) ? 2 : 1);
      for (int pa = 0; pa < npa; ++pa)
#pragma unroll
        for (int mt = 0; mt < 4; ++mt)
#pragma unroll
          for (int nt = 0; nt < 4; ++nt)
            acc[mt][nt] = MFMA16(af[pa][mt], bfr[nt], acc[mt][nt], 0, 0, 0);
    }
  }
#pragma unroll
  for (int mt = 0; mt < 4; ++mt)
#pragma unroll
    for (int reg = 0; reg < 4; ++reg) {
      int r = m0 + wm + mt * 16 + quad * 4 + reg;
      if (r < mEnd) {
        long lr = r - c0;
#pragma unroll
        for (int nt = 0; nt < 4; ++nt) {
          int n = n0 + wn + nt * 16 + ln15;
          U[lr * 2048 + n] = fmaxf(acc[mt][nt][reg] + b1F[n], 0.f);
        }
      }
    }
}

// ---------- GEMM2: h = U*W2 + b2; state/prev update; halting for t+1 ------
// A: U fp32 local rows; B: W2T planes; K=2048 (64 kt), N=512.
// Epilogue: writes per-strip partials of dot(h,Wp) to pdot8[pos][slot]
// (release, agent scope), then fetch_add(rowcnt[pos], acq_rel); the 8th
// writer sums slots 0..7 in fixed order (== old k_plite sum), performs the
// t+1 halting update and compacts into ridx[t+1]. Deterministic: fixed-order
// sum, single-writer state updates. No spin waits (no deadlock possible).
__global__ __launch_bounds__(256) void k_gemm2(
    const float* __restrict__ U, const unsigned short* __restrict__ w2t,
    const float* __restrict__ b2F, const int* __restrict__ count,
    const int* __restrict__ ridxAll, const float* __restrict__ maskF,
    float* __restrict__ uw, const float* __restrict__ WpF,
    const float* __restrict__ edot, const float* __restrict__ bpF,
    float* __restrict__ stateF, float* __restrict__ prevF,
    float* __restrict__ pdot8, int* __restrict__ rowcnt, float* hp,
    float* rem, float* nup, int* counts, int* ridxW, int c0, int mc, int t) {
  const int* ridx = ridxAll + (long)t * 16384;
  int Ma = *count;
  int mEnd = c0 + mc;
  if (Ma < mEnd) mEnd = Ma;
  int f = blockIdx.x;
  int x = f & 7, s = f >> 3;
  int n0 = (x >> 1) * 128;
  int m0 = c0 + (s * 2 + (x & 1)) * 128;
  if (m0 >= mEnd) return;
  __shared__ __align__(16) float Au[4][2][128][4];          // 16 KB fp32 A
  __shared__ __align__(16) unsigned short Bs[3][4][128][8]; // 24 KB B planes
  int tid = threadIdx.x;
  int lane = tid & 63, wv = tid >> 6;
  int quad = lane >> 4, ln15 = lane & 15;
  int wm = (wv >> 1) << 6, wn = (wv & 1) << 6;
  long lr0 = (long)(m0 - c0) + lane;
  long lr1 = lr0 + 64;
  f32x4 acc[4][4];
#pragma unroll
  for (int i = 0; i < 4; i++)
#pragma unroll
    for (int j = 0; j < 4; j++) acc[i][j] = (f32x4)0.f;
#pragma unroll 1
  for (int kt = 0; kt < 64; ++kt) {
    __syncthreads();
#pragma unroll
    for (int i = 0; i < 4; ++i) {  // A staging fp32
      int g = wv + 4 * i;
      int q = g >> 2, h = (g >> 1) & 1, rh = g & 1;
      long lr = rh ? lr1 : lr0;
      gld16(U + lr * 2048 + kt * 32 + q * 8 + h * 4, &Au[q][h][rh * 64][0]);
    }
#pragma unroll
    for (int i = 0; i < 6; ++i) {  // B staging
      int g = wv + 4 * i;
      int p = g >> 3, q = (g >> 1) & 3, rh = g & 1;
      long n = n0 + rh * 64 + lane;
      gld16(w2t + (long)p * 1048576L + n * 2048 + kt * 32 + q * 8,
            &Bs[p][q][rh * 64][0]);
    }
    __syncthreads();
    short8 af[3][4];
#pragma unroll
    for (int mt = 0; mt < 4; ++mt) {
      int row = wm + mt * 16 + ln15;
      f4 x0 = *(const f4*)&Au[quad][0][row][0];
      f4 x1 = *(const f4*)&Au[quad][1][row][0];
      float xs[8];
      xs[0] = x0.x; xs[1] = x0.y; xs[2] = x0.z; xs[3] = x0.w;
      xs[4] = x1.x; xs[5] = x1.y; xs[6] = x1.z; xs[7] = x1.w;
#pragma unroll
      for (int j = 0; j < 8; ++j) {
        unsigned short h_, m_, l_;
        split3(xs[j], h_, m_, l_);
        ((unsigned short*)&af[0][mt])[j] = h_;
        ((unsigned short*)&af[1][mt])[j] = m_;
        ((unsigned short*)&af[2][mt])[j] = l_;
      }
    }
#pragma unroll
    for (int pb = 0; pb < 3; ++pb) {
      short8 bfr[4];
#pragma unroll
      for (int nt = 0; nt < 4; ++nt)
        bfr[nt] = *(const short8*)&Bs[pb][quad][wn + nt * 16 + ln15][0];
      int npa = (pb == 0) ? 3 : ((pb == 1) ? 2 : 1);
      for (int pa = 0; pa < npa; ++pa)
#pragma unroll
        for (int mt = 0; mt < 4; ++mt)
#pragma unroll
          for (int nt = 0; nt < 4; ++nt)
            acc[mt][nt] = MFMA16(af[pa][mt], bfr[nt], acc[mt][nt], 0, 0, 0);
    }
  }
#pragma unroll
  for (int mt = 0; mt < 4; ++mt)
#pragma unroll
    for (int reg = 0; reg < 4; ++reg) {
      int r = m0 + wm + mt * 16 + quad * 4 + reg;
      // r uniform across the 16 ln15 lanes of each quad-group.
      if (r < mEnd) {
        long pos = (long)ridx[r];
        float mk = maskF[pos];
        float uv = uw[pos];
        float pd = 0.f;
#pragma unroll
        for (int nt = 0; nt < 4; ++nt) {
          int n = n0 + wn + nt * 16 + ln15;
          float h = (acc[mt][nt][reg] + b2F[n]) * mk;
          long off = pos * 512 + n;
          stateF[off] = h;
          prevF[off] = fmaf(h, uv, prevF[off]);
          pd = fmaf(h, WpF[n], pd);
        }
        pd += __shfl_xor(pd, 1, 64);
        pd += __shfl_xor(pd, 2, 64);
        pd += __shfl_xor(pd, 4, 64);
        pd += __shfl_xor(pd, 8, 64);
        if (ln15 == 0) {
          int slot = (n0 >> 7) * 2 + (wv & 1);
          __hip_atomic_store(&pdot8[pos * 8 + slot], pd, __ATOMIC_RELEASE,
                             __HIP_MEMORY_SCOPE_AGENT);
          int old = __hip_atomic_fetch_add(&rowcnt[pos], 1, __ATOMIC_ACQ_REL,
                                           __HIP_MEMORY_SCOPE_AGENT);
          if (old == 7) {  // 8th writer: all slots visible (acq_rel chain)
            __hip_atomic_store(&rowcnt[pos], 0, __ATOMIC_RELAXED,
                               __HIP_MEMORY_SCOPE_AGENT);
            float s8 = 0.f;
#pragma unroll
            for (int k = 0; k < 8; ++k) {
              float v = __hip_atomic_load(&pdot8[pos * 8 + k],
                                          __ATOMIC_RELAXED,
                                          __HIP_MEMORY_SCOPE_AGENT);
              s8 = (k == 0) ? v : s8 + v;
            }
            if (t < 10) {
              float hpv = hp[pos];
              if (hpv < 1.0f) {
                float p = 1.0f / (1.0f + expf(-(s8 + edot[t + 1] + bpF[0])));
                float q = hpv + p;
                float nh = (q > THR) ? 1.0f : 0.0f;
                float st2 = (q <= THR) ? 1.0f : 0.0f;
                float hpn = hpv + p * st2;
                float remn = rem[pos] + nh * (1.0f - hpn);
                hpn = hpn + nh * remn;
                nup[pos] = nup[pos] + st2 + nh;
                uw[pos] = p * st2 + nh * remn;
                hp[pos] = hpn;
                rem[pos] = remn;
                int idx = atomicAdd(counts + t + 1, 1);
                ridxW[(long)(t + 1) * 16384 + idx] = (int)pos;
              }
            }
          }
        }
      }
    }
}

// ---------- final: concat outputs, cast per detected dtype ----------
__global__ void k_final(const float* prevF, const float* nupF,
                        const float* remF, void* out, const void* mask) {
  int bf = detect_bf(mask);
  long gt = (long)blockIdx.x * 256 + threadIdx.x;
  long gs = (long)gridDim.x * 256;
  for (long i = gt; i < 8421376L; i += gs) {
    float v;
    if (i < 8388608L) v = prevF[i];
    else if (i < 8404992L) v = nupF[i - 8388608L];
    else v = remF[i - 8404992L];
    if (bf) ((__hip_bfloat16*)out)[i] = __float2bfloat16(v);
    else ((float*)out)[i] = v;
  }
}

extern "C" void kernel_launch(void* const* d_in, const int* in_sizes, int n_in,
                              void* d_out, int out_size, void* d_ws,
                              size_t ws_size, hipStream_t stream) {
  const void* state = d_in[0];
  const void* mask = d_in[1];
  const void* emb = d_in[2];
  const void* Wp = d_in[3];
  const void* bp = d_in[4];
  const void* W1 = d_in[5];
  const void* b1 = d_in[6];
  const void* W2 = d_in[7];
  const void* b2 = d_in[8];
  char* w = (char*)d_ws;
  float* stateF = (float*)(w + 0L);
  float* prevF = (float*)(w + 33554432L);
  unsigned short* w1t = (unsigned short*)(w + 67108864L);  // 3 x 2 MB
  unsigned short* w2t = (unsigned short*)(w + 73400320L);  // 3 x 2 MB
  float* maskF = (float*)(w + 79691776L);
  float* hp = (float*)(w + 79757312L);
  float* rem = (float*)(w + 79822848L);
  float* nup = (float*)(w + 79888384L);
  float* uwf = (float*)(w + 79953920L);
  float* embF = (float*)(w + 80019456L);
  float* WpF = (float*)(w + 80052224L);
  float* b1F = (float*)(w + 80056320L);
  float* b2F = (float*)(w + 80064512L);
  float* bpF = (float*)(w + 80068608L);
  int* counts = (int*)(w + 80069120L);    // 11 ints
  float* edot = (float*)(w + 80069632L);  // 11 floats
  int* ridx = (int*)(w + 80070144L);      // 11 x 16384 x 4 B
  float* pdot8 = (float*)(w + 80791040L); // 16384 x 8 fp32 = 512 KB
  int* rowcnt = (int*)(w + 81315328L);    // 16384 ints = 64 KB
  float* U = (float*)(w + 81380864L);     // fp32 [Mc][2048]
  long ub = (long)ws_size - 81380864L;
  long rows = ub / 8192L;
  long McL = rows & ~255L;  // multiple of 256 so T=mc/128 stays even
  if (McL > 16384L) McL = 16384L;
  if (McL < 256L) McL = 256L;
  int Mc = (int)McL;
  int nCh = (16384 + Mc - 1) / Mc;

  k_prep<<<64, 256, 0, stream>>>(mask, emb, Wp, bp, b1, b2, embF, WpF, bpF,
                                 b1F, b2F, edot, counts, rowcnt);
  k_init<<<2048, 256, 0, stream>>>(state, W1, W2, mask, Wp, edot, bpF, stateF,
                                   w1t, w2t, maskF, prevF, hp, rem, nup, uwf,
                                   counts, ridx);
  for (int t = 0; t <= 10; t++) {
    for (int c = 0; c < nCh; c++) {
      int c0 = c * Mc;
      int mc = 16384 - c0;
      if (mc > Mc) mc = Mc;
      int T = mc / 128;  // even (Mc multiple of 256, 16384 multiple of 256)
      k_gemm1<<<T * 16, 256, 0, stream>>>(stateF, embF + t * 512, w1t, b1F,
                                          counts + t, ridx + (long)t * 16384,
                                          U, c0, mc);
      k_gemm2<<<T * 4, 256, 0, stream>>>(U, w2t, b2F, counts + t, ridx, maskF,
                                         uwf, WpF, edot, bpF, stateF, prevF,
                                         pdot8, rowcnt, hp, rem, nup, counts,
                                         ridx, c0, mc, t);
    }
  }
  k_final<<<2048, 256, 0, stream>>>(prevF, nup, rem, d_out, mask);
}

// Round 11
// 2554.432 us; speedup vs baseline: 1.9258x; 1.9258x over previous
//
#include <hip/hip_runtime.h>
#include <hip/hip_bf16.h>
#include <stdint.h>

// ACT (adaptive computation time) on MI355X.
// R16: pure-plane GEMMs via linearity. R15 post-mortem: agent-scope
// release/acq_rel atomics in gemm2's epilogue = per-store L2 writebacks on
// 8 non-coherent XCDs -> 1640us @ MfmaUtil 5% (same mechanism as R10's
// grid.sync disaster). Protocol reverted to R14 (plain stores + k_plite
// across dispatch boundaries). The new lever: R14's GEMMs are co-bound by
// VALUBusy ~36% = the per-kt register split3 of fp32 A (~300 VALU cy/kt).
// Remove it algebraically: (state+emb)*W1 = state*W1 + emb*W1, so
// k_prep precomputes E1[t] = emb_t*W1 + b1 (11x2048 fp32) and gemm1 adds
// E1 in the epilogue. A-sides become bf16x3 PLANES: gemm2's epilogue writes
// split3(h) state planes (sPl; k_init seeds t=0), gemm1's epilogue writes
// split3(relu(...)) U planes (uPl). Both K-loops: stage A+B planes (24+24KB,
// same 1KB-region pattern, 0 conflicts verified) -> 24 ds_read_b128 ->
// 96 MFMA; per-kt VALU ~300 -> ~40 cy. 48KB static LDS -> 3 blocks/CU.
// fp32 stateF/U deleted. Accumulation order kt->pb->pa->mt->nt unchanged;
// emb contribution now exact-linear fp32 (same rounding class as the
// validated pdot8 re-association).

#define THR 0.99f
typedef float4 f4;
typedef __attribute__((ext_vector_type(8))) short short8;
typedef __attribute__((ext_vector_type(4))) float f32x4;

__device__ __forceinline__ int detect_bf(const void* mask) {
  return (((const unsigned int*)mask)[0] == 0x3F803F80u) ? 1 : 0;
}

__device__ __forceinline__ float ld_in(const void* p, long i, int bf) {
  if (bf) {
    unsigned short u = ((const unsigned short*)p)[i];
    return __uint_as_float(((unsigned int)u) << 16);
  }
  return ((const float*)p)[i];
}
__device__ __forceinline__ f4 ld4(const float* p) { return *(const f4*)p; }

// truncation 3-way bf16 split: x ~= h + m + l, |err| <= 2^-24|x|
__device__ __forceinline__ void split3(float x, unsigned short& h,
                                       unsigned short& m, unsigned short& l) {
  unsigned u = __float_as_uint(x);
  h = (unsigned short)(u >> 16);
  float fh = __uint_as_float(u & 0xFFFF0000u);
  float r = x - fh;  // exact
  unsigned v = __float_as_uint(r);
  m = (unsigned short)(v >> 16);
  float fm = __uint_as_float(v & 0xFFFF0000u);
  l = (unsigned short)(__float_as_uint(r - fm) >> 16);
}

__device__ __forceinline__ void gld16(const void* g, void* l) {
  __builtin_amdgcn_global_load_lds(
      (const __attribute__((address_space(1))) void*)g,
      (__attribute__((address_space(3))) void*)l, 16, 0, 0);
}

#define MFMA16 __builtin_amdgcn_mfma_f32_16x16x32_bf16

// ---------- prep: params + E1[t] = emb_t*W1 + b1 + edot + counters --------
__global__ __launch_bounds__(256) void k_prep(
    const void* mask, const void* emb, const void* Wp, const void* bp,
    const void* b1, const void* b2, const void* W1, float* WpF, float* bpF,
    float* b2F, float* E1, float* edot, int* counts) {
  int bf = detect_bf(mask);
  int tid = threadIdx.x;
  long gt = (long)blockIdx.x * 256 + tid;
  long gs = (long)gridDim.x * 256;
  for (long i = gt; i < 512; i += gs) {
    WpF[i] = ld_in(Wp, i, bf);
    b2F[i] = ld_in(b2, i, bf);
  }
  if (gt < 11) counts[gt] = 0;
  if (gt == 0) bpF[0] = ld_in(bp, 0, bf);
  // E1[t][n] = dot(emb_t, W1[:,n]) + b1[n]; n-consecutive threads coalesce
  // on W1 rows; emb_t broadcast within a t-group.
  for (long i = gt; i < 22528; i += gs) {
    int t = (int)(i >> 11), n = (int)(i & 2047);
    float acc = 0.f;
    for (int k = 0; k < 512; ++k)
      acc = fmaf(ld_in(emb, (long)t * 512 + k, bf),
                 ld_in(W1, (long)k * 2048 + n, bf), acc);
    E1[i] = acc + ld_in(b1, n, bf);
  }
  // edot[t] = dot(emb_t, Wp): blocks 0..10, wave 0
  int lane = tid & 63, wv = tid >> 6;
  if (blockIdx.x < 11 && wv == 0) {
    int t = blockIdx.x;
    int d = lane * 8;
    float acc = 0.f;
#pragma unroll
    for (int j = 0; j < 8; ++j) {
      float wpv = ld_in(Wp, d + j, bf);
      float ev = ld_in(emb, (long)t * 512 + d + j, bf);
      acc = (j == 0) ? ev * wpv : fmaf(ev, wpv, acc);
    }
#pragma unroll
    for (int off = 32; off > 0; off >>= 1) acc += __shfl_xor(acc, off, 64);
    if (lane == 0) edot[t] = acc;
  }
}

// ---------- init: state planes + weight split + t=0 halting ---------------
// Row pass: 2048 blocks x 4 waves x 2 rows. Each wave split3s its rows into
// sPl planes, zeroes prevF, reduces dot(row,Wp); lane 0 performs the t=0
// halting update + compaction into ridx[0] (validated in R15's pass).
__global__ __launch_bounds__(256) void k_init(
    const void* state, const void* W1, const void* W2, const void* mask,
    const void* Wp, const float* __restrict__ edot,
    const float* __restrict__ bpF, unsigned short* sPl, unsigned short* w1t,
    unsigned short* w2t, float* maskF, float* prevF, float* hp, float* rem,
    float* nup, float* uw, int* counts0, int* ridx0) {
  int bf = detect_bf(mask);
  int tid = threadIdx.x;
  int lane = tid & 63, wv = tid >> 6;
  int d = lane * 8;
  float wp[8];
#pragma unroll
  for (int j = 0; j < 8; ++j) wp[j] = ld_in(Wp, d + j, bf);
#pragma unroll 1
  for (int r = 0; r < 2; ++r) {
    long row = ((long)blockIdx.x * 4 + wv) * 2 + r;
    long base = row * 512 + d;
    float sv[8];
#pragma unroll
    for (int j = 0; j < 8; ++j) sv[j] = ld_in(state, base + j, bf);
    short8 ph, pm, pl;
#pragma unroll
    for (int j = 0; j < 8; ++j) {
      unsigned short h_, m_, l_;
      split3(sv[j], h_, m_, l_);
      ((unsigned short*)&ph)[j] = h_;
      ((unsigned short*)&pm)[j] = m_;
      ((unsigned short*)&pl)[j] = l_;
    }
    *(short8*)&sPl[base] = ph;
    *(short8*)&sPl[8388608L + base] = pm;
    *(short8*)&sPl[16777216L + base] = pl;
    *(f4*)&prevF[base] = (f4){0.f, 0.f, 0.f, 0.f};
    *(f4*)&prevF[base + 4] = (f4){0.f, 0.f, 0.f, 0.f};
    float acc = sv[0] * wp[0];
#pragma unroll
    for (int j = 1; j < 8; ++j) acc = fmaf(sv[j], wp[j], acc);
#pragma unroll
    for (int off = 32; off > 0; off >>= 1) acc += __shfl_xor(acc, off, 64);
    if (lane == 0) {
      float p = 1.0f / (1.0f + expf(-(acc + edot[0] + bpF[0])));
      float q = p;
      float nh = (q > THR) ? 1.0f : 0.0f;
      float st2 = (q <= THR) ? 1.0f : 0.0f;
      float hpn = p * st2;
      float remn = nh * (1.0f - hpn);
      hpn = hpn + nh * remn;
      nup[row] = st2 + nh;
      uw[row] = p * st2 + nh * remn;
      hp[row] = hpn;
      rem[row] = remn;
      int idx = atomicAdd(counts0, 1);
      ridx0[idx] = (int)row;
    }
  }
  long t = (long)blockIdx.x * blockDim.x + tid;
  long st = (long)gridDim.x * blockDim.x;
  // W1 [512][2048] -> W1T planes [2048][512] bf16 x3 (plane stride 1048576)
  for (long i = t; i < 1048576L; i += st) {
    float v = ld_in(W1, i, bf);
    long n = i & 2047, k = i >> 11;
    unsigned short h, m, l;
    split3(v, h, m, l);
    long o = n * 512 + k;
    w1t[o] = h;
    w1t[1048576L + o] = m;
    w1t[2097152L + o] = l;
  }
  // W2 [2048][512] -> W2T planes [512][2048] bf16 x3
  for (long i = t; i < 1048576L; i += st) {
    float v = ld_in(W2, i, bf);
    long k = i >> 9, n = i & 511;
    unsigned short h, m, l;
    split3(v, h, m, l);
    long o = n * 2048 + k;
    w2t[o] = h;
    w2t[1048576L + o] = m;
    w2t[2097152L + o] = l;
  }
  for (long i = t; i < 16384L; i += st) maskF[i] = ld_in(mask, i, bf);
}

// ---------- ponder-lite: 1 thread / position, no state read (R14) ---------
__global__ __launch_bounds__(256) void k_plite(
    const float* __restrict__ pdot8, const float* __restrict__ edot,
    const float* __restrict__ bpF, float* hp, float* rem, float* nup,
    float* uw, int* __restrict__ count, int* __restrict__ ridx, int t) {
  int pos = blockIdx.x * 256 + threadIdx.x;
  float hpv = hp[pos];
  if (hpv >= 1.0f) return;  // halted forever
  const float* pd = pdot8 + (long)pos * 8;
  float s8 = pd[0];
#pragma unroll
  for (int k = 1; k < 8; ++k) s8 += pd[k];
  float p = 1.0f / (1.0f + expf(-(s8 + edot[t] + bpF[0])));
  float q = hpv + p;
  float nh = (q > THR) ? 1.0f : 0.0f;
  float st2 = (q <= THR) ? 1.0f : 0.0f;
  float hpn = hpv + p * st2;
  float remn = rem[pos] + nh * (1.0f - hpn);
  hpn = hpn + nh * remn;
  nup[pos] = nup[pos] + st2 + nh;
  uw[pos] = p * st2 + nh * remn;
  hp[pos] = hpn;
  rem[pos] = remn;
  int idx = atomicAdd(count, 1);
  ridx[idx] = pos;
}

// LDS (static, both GEMMs): As bf16 planes [3][4][128][8] = 24 KB;
// Bs bf16 planes [3][4][128][8] = 24 KB. 48 KB -> 3 blocks/CU.
// Stage region = 1KB (64 lanes x 16B); layouts verified 0-conflict (R5/R7).

// ---------- GEMM1: uPl = split3(relu(sPl_planes*W1 + E1[t])) --------------
// A: sPl planes gathered via ridx; B: W1T planes; K=512 (16 kt), N=2048.
__global__ __launch_bounds__(256) void k_gemm1(
    const unsigned short* __restrict__ sPl, const float* __restrict__ E1t,
    const unsigned short* __restrict__ w1t, const int* __restrict__ count,
    const int* __restrict__ ridx, unsigned short* __restrict__ uPl,
    long upStr, int c0, int mc) {
  int Ma = *count;
  int mEnd = c0 + mc;
  if (Ma < mEnd) mEnd = Ma;
  int f = blockIdx.x;
  int x = f & 7, s = f >> 3;
  int n0 = (x * 2 + (s & 1)) * 128;
  int m0 = c0 + (s >> 1) * 128;
  if (m0 >= mEnd) return;
  __shared__ __align__(16) unsigned short As[3][4][128][8];  // 24 KB
  __shared__ __align__(16) unsigned short Bs[3][4][128][8];  // 24 KB
  int tid = threadIdx.x;
  int lane = tid & 63, wv = tid >> 6;
  int quad = lane >> 4, ln15 = lane & 15;
  int wm = (wv >> 1) << 6, wn = (wv & 1) << 6;
  int rr0 = m0 + lane;
  if (rr0 >= mEnd) rr0 = mEnd - 1;
  int rr1 = m0 + 64 + lane;
  if (rr1 >= mEnd) rr1 = mEnd - 1;
  long pos0 = ridx[rr0], pos1 = ridx[rr1];
  f32x4 acc[4][4];
#pragma unroll
  for (int i = 0; i < 4; i++)
#pragma unroll
    for (int j = 0; j < 4; j++) acc[i][j] = (f32x4)0.f;
#pragma unroll 1
  for (int kt = 0; kt < 16; ++kt) {
    __syncthreads();
#pragma unroll
    for (int i = 0; i < 6; ++i) {  // A plane staging (gather)
      int g = wv + 4 * i;
      int p = g >> 3, q = (g >> 1) & 3, rh = g & 1;
      long po = rh ? pos1 : pos0;
      gld16(sPl + (long)p * 8388608L + po * 512 + kt * 32 + q * 8,
            &As[p][q][rh * 64][0]);
    }
#pragma unroll
    for (int i = 0; i < 6; ++i) {  // B plane staging
      int g = wv + 4 * i;
      int p = g >> 3, q = (g >> 1) & 3, rh = g & 1;
      long n = n0 + rh * 64 + lane;
      gld16(w1t + (long)p * 1048576L + n * 512 + kt * 32 + q * 8,
            &Bs[p][q][rh * 64][0]);
    }
    __syncthreads();
    short8 af[3][4];
#pragma unroll
    for (int p = 0; p < 3; ++p)
#pragma unroll
      for (int mt = 0; mt < 4; ++mt)
        af[p][mt] = *(const short8*)&As[p][quad][wm + mt * 16 + ln15][0];
#pragma unroll
    for (int pb = 0; pb < 3; ++pb) {
      short8 bfr[4];
#pragma unroll
      for (int nt = 0; nt < 4; ++nt)
        bfr[nt] = *(const short8*)&Bs[pb][quad][wn + nt * 16 + ln15][0];
      int npa = (pb == 0) ? 3 : ((pb == 1) ? 2 : 1);
      for (int pa = 0; pa < npa; ++pa)
#pragma unroll
        for (int mt = 0; mt < 4; ++mt)
#pragma unroll
          for (int nt = 0; nt < 4; ++nt)
            acc[mt][nt] = MFMA16(af[pa][mt], bfr[nt], acc[mt][nt], 0, 0, 0);
    }
  }
#pragma unroll
  for (int mt = 0; mt < 4; ++mt)
#pragma unroll
    for (int reg = 0; reg < 4; ++reg) {
      int r = m0 + wm + mt * 16 + quad * 4 + reg;
      if (r < mEnd) {
        long lr = r - c0;
#pragma unroll
        for (int nt = 0; nt < 4; ++nt) {
          int n = n0 + wn + nt * 16 + ln15;
          float u = fmaxf(acc[mt][nt][reg] + E1t[n], 0.f);
          unsigned short h_, m_, l_;
          split3(u, h_, m_, l_);
          long o = lr * 2048 + n;
          uPl[o] = h_;
          uPl[upStr + o] = m_;
          uPl[2 * upStr + o] = l_;
        }
      }
    }
}

// ---------- GEMM2: h = uPl*W2 + b2; sPl=split3(h*mask); prev += h*uw ------
// A: uPl planes (local rows); B: W2T planes; K=2048 (64 kt), N=512.
// Epilogue: prevF fmaf, state planes, pdot8 per-strip partials (plain
// stores, read next dispatch by k_plite — R14 protocol, no atomics).
__global__ __launch_bounds__(256) void k_gemm2(
    const unsigned short* __restrict__ uPl,
    const unsigned short* __restrict__ w2t, const float* __restrict__ b2F,
    const int* __restrict__ count, const int* __restrict__ ridx,
    const float* __restrict__ maskF, const float* __restrict__ uwF,
    const float* __restrict__ WpF, unsigned short* __restrict__ sPl,
    float* __restrict__ prevF, float* __restrict__ pdot8, long upStr, int c0,
    int mc) {
  int Ma = *count;
  int mEnd = c0 + mc;
  if (Ma < mEnd) mEnd = Ma;
  int f = blockIdx.x;
  int x = f & 7, s = f >> 3;
  int n0 = (x >> 1) * 128;
  int m0 = c0 + (s * 2 + (x & 1)) * 128;
  if (m0 >= mEnd) return;
  __shared__ __align__(16) unsigned short As[3][4][128][8];  // 24 KB
  __shared__ __align__(16) unsigned short Bs[3][4][128][8];  // 24 KB
  int tid = threadIdx.x;
  int lane = tid & 63, wv = tid >> 6;
  int quad = lane >> 4, ln15 = lane & 15;
  int wm = (wv >> 1) << 6, wn = (wv & 1) << 6;
  long lr0 = (long)(m0 - c0) + lane;
  long lr1 = lr0 + 64;
  f32x4 acc[4][4];
#pragma unroll
  for (int i = 0; i < 4; i++)
#pragma unroll
    for (int j = 0; j < 4; j++) acc[i][j] = (f32x4)0.f;
#pragma unroll 1
  for (int kt = 0; kt < 64; ++kt) {
    __syncthreads();
#pragma unroll
    for (int i = 0; i < 6; ++i) {  // A plane staging (local rows)
      int g = wv + 4 * i;
      int p = g >> 3, q = (g >> 1) & 3, rh = g & 1;
      long lr = rh ? lr1 : lr0;
      gld16(uPl + (long)p * upStr + lr * 2048 + kt * 32 + q * 8,
            &As[p][q][rh * 64][0]);
    }
#pragma unroll
    for (int i = 0; i < 6; ++i) {  // B plane staging
      int g = wv + 4 * i;
      int p = g >> 3, q = (g >> 1) & 3, rh = g & 1;
      long n = n0 + rh * 64 + lane;
      gld16(w2t + (long)p * 1048576L + n * 2048 + kt * 32 + q * 8,
            &Bs[p][q][rh * 64][0]);
    }
    __syncthreads();
    short8 af[3][4];
#pragma unroll
    for (int p = 0; p < 3; ++p)
#pragma unroll
      for (int mt = 0; mt < 4; ++mt)
        af[p][mt] = *(const short8*)&As[p][quad][wm + mt * 16 + ln15][0];
#pragma unroll
    for (int pb = 0; pb < 3; ++pb) {
      short8 bfr[4];
#pragma unroll
      for (int nt = 0; nt < 4; ++nt)
        bfr[nt] = *(const short8*)&Bs[pb][quad][wn + nt * 16 + ln15][0];
      int npa = (pb == 0) ? 3 : ((pb == 1) ? 2 : 1);
      for (int pa = 0; pa < npa; ++pa)
#pragma unroll
        for (int mt = 0; mt < 4; ++mt)
#pragma unroll
          for (int nt = 0; nt < 4; ++nt)
            acc[mt][nt] = MFMA16(af[pa][mt], bfr[nt], acc[mt][nt], 0, 0, 0);
    }
  }
#pragma unroll
  for (int mt = 0; mt < 4; ++mt)
#pragma unroll
    for (int reg = 0; reg < 4; ++reg) {
      int r = m0 + wm + mt * 16 + quad * 4 + reg;
      // r uniform across the 16 ln15 lanes of each quad-group.
      if (r < mEnd) {
        long pos = (long)ridx[r];
        float mk = maskF[pos];
        float uv = uwF[pos];
        float pd = 0.f;
#pragma unroll
        for (int nt = 0; nt < 4; ++nt) {
          int n = n0 + wn + nt * 16 + ln15;
          float h = (acc[mt][nt][reg] + b2F[n]) * mk;
          long off = pos * 512 + n;
          prevF[off] = fmaf(h, uv, prevF[off]);
          unsigned short h_, m_, l_;
          split3(h, h_, m_, l_);
          sPl[off] = h_;
          sPl[8388608L + off] = m_;
          sPl[16777216L + off] = l_;
          pd = fmaf(h, WpF[n], pd);
        }
        pd += __shfl_xor(pd, 1, 64);
        pd += __shfl_xor(pd, 2, 64);
        pd += __shfl_xor(pd, 4, 64);
        pd += __shfl_xor(pd, 8, 64);
        if (ln15 == 0)
          pdot8[pos * 8 + (long)((n0 >> 7) * 2 + (wv & 1))] = pd;
      }
    }
}

// ---------- final: concat outputs, cast per detected dtype ----------
__global__ void k_final(const float* prevF, const float* nupF,
                        const float* remF, void* out, const void* mask) {
  int bf = detect_bf(mask);
  long gt = (long)blockIdx.x * 256 + threadIdx.x;
  long gs = (long)gridDim.x * 256;
  for (long i = gt; i < 8421376L; i += gs) {
    float v;
    if (i < 8388608L) v = prevF[i];
    else if (i < 8404992L) v = nupF[i - 8388608L];
    else v = remF[i - 8404992L];
    if (bf) ((__hip_bfloat16*)out)[i] = __float2bfloat16(v);
    else ((float*)out)[i] = v;
  }
}

extern "C" void kernel_launch(void* const* d_in, const int* in_sizes, int n_in,
                              void* d_out, int out_size, void* d_ws,
                              size_t ws_size, hipStream_t stream) {
  const void* state = d_in[0];
  const void* mask = d_in[1];
  const void* emb = d_in[2];
  const void* Wp = d_in[3];
  const void* bp = d_in[4];
  const void* W1 = d_in[5];
  const void* b1 = d_in[6];
  const void* W2 = d_in[7];
  const void* b2 = d_in[8];
  char* w = (char*)d_ws;
  unsigned short* sPl = (unsigned short*)(w + 0L);      // 3 x 16 MB planes
  float* prevF = (float*)(w + 50331648L);               // 32 MB
  unsigned short* w1t = (unsigned short*)(w + 83886080L);  // 3 x 2 MB
  unsigned short* w2t = (unsigned short*)(w + 90177536L);  // 3 x 2 MB
  float* maskF = (float*)(w + 96468992L);
  float* hp = (float*)(w + 96534528L);
  float* rem = (float*)(w + 96600064L);
  float* nup = (float*)(w + 96665600L);
  float* uwf = (float*)(w + 96731136L);
  float* WpF = (float*)(w + 96796672L);
  float* b2F = (float*)(w + 96798720L);
  float* bpF = (float*)(w + 96800768L);
  float* edot = (float*)(w + 96801024L);  // 11 floats
  int* counts = (int*)(w + 96801088L);    // 11 ints
  float* E1 = (float*)(w + 96801152L);    // 11 x 2048 fp32
  int* ridx = (int*)(w + 96891264L);      // 11 x 16384 x 4 B
  float* pdot8 = (float*)(w + 97612160L); // 16384 x 8 fp32 = 512 KB
  unsigned short* uPl = (unsigned short*)(w + 98136448L);  // bf16x3 U planes
  long ub = (long)ws_size - 98136448L;
  long rows = ub / 12288L;  // 3 planes x 2048 x 2B per row
  long McL = rows & ~255L;  // multiple of 256 so T=mc/128 stays even
  if (McL > 16384L) McL = 16384L;
  if (McL < 256L) McL = 256L;
  int Mc = (int)McL;
  int nCh = (16384 + Mc - 1) / Mc;
  long upStr = (long)Mc * 2048L;

  k_prep<<<96, 256, 0, stream>>>(mask, emb, Wp, bp, b1, b2, W1, WpF, bpF, b2F,
                                 E1, edot, counts);
  k_init<<<2048, 256, 0, stream>>>(state, W1, W2, mask, Wp, edot, bpF, sPl,
                                   w1t, w2t, maskF, prevF, hp, rem, nup, uwf,
                                   counts, ridx);
  for (int t = 0; t <= 10; t++) {
    if (t > 0)
      k_plite<<<64, 256, 0, stream>>>(pdot8, edot, bpF, hp, rem, nup, uwf,
                                      counts + t, ridx + (long)t * 16384, t);
    for (int c = 0; c < nCh; c++) {
      int c0 = c * Mc;
      int mc = 16384 - c0;
      if (mc > Mc) mc = Mc;
      int T = mc / 128;  // even (Mc multiple of 256, 16384 multiple of 256)
      k_gemm1<<<T * 16, 256, 0, stream>>>(sPl, E1 + (long)t * 2048, w1t,
                                          counts + t, ridx + (long)t * 16384,
                                          uPl, upStr, c0, mc);
      k_gemm2<<<T * 4, 256, 0, stream>>>(uPl, w2t, b2F, counts + t,
                                         ridx + (long)t * 16384, maskF, uwf,
                                         WpF, sPl, prevF, pdot8, upStr, c0,
                                         mc);
    }
  }
  k_final<<<2048, 256, 0, stream>>>(prevF, nup, rem, d_out, mask);
}